// Round 5
// baseline (1154.966 us; speedup 1.0000x reference)
//
#include <hip/hip_runtime.h>
#include <hip/hip_bf16.h>
#include <stdint.h>

// ---------------------------------------------------------------------------
// LSTM cell, fused as one bf16 MFMA GEMM:
//   A  = [input | hidden]            : [16384][2048]  (bf16, packed in ws)
//   W  = [Wx[g] | Wh[g]] per gate g  : [4096][2048]   (bf16, packed in ws, [N][K])
//   pre[g][b][s] = sum_k A[b][k] * W[g*1024+s][k] + bias[g][s]
// Each GEMM block computes one 128x64 tile for ALL 4 gates with a fused
// sigmoid/tanh/cell epilogue (no pre[] materialization).
//
// Round 5 change (single variable): __launch_bounds__(512, 2) -> (512, 1).
// Evidence across r2-r4: WRITE_SIZE ~2.9GB constant (outputs are 134MB),
// VGPR_Count tracks the launch_bounds arg (124 @ (256,2), 64 @ (512,2)) --
// hipcc derives a hard register budget from the min-occupancy arg and
// spills the staging regs/addresses to scratch every K-iter. 2048 blk x
// 512 thr x 32 iter x ~85B = 2.8GB = measured write traffic, which at
// 3.7TB/s accounts for the full kernel duration. Lifting the budget to
// ~256 regs (need ~165: 64 acc + ~100 arch) should eliminate scratch.
// ---------------------------------------------------------------------------

typedef short bf16x8 __attribute__((ext_vector_type(8)));
typedef float f32x4 __attribute__((ext_vector_type(4)));

#define B_ROWS 16384
#define D_K 2048

__device__ __forceinline__ unsigned short f2bf(float f) {
    unsigned u = __builtin_bit_cast(unsigned, f);
    u += 0x7FFFu + ((u >> 16) & 1u);   // round-to-nearest-even
    return (unsigned short)(u >> 16);
}

__device__ __forceinline__ float sigf(float x) { return 1.0f / (1.0f + __expf(-x)); }
__device__ __forceinline__ float tanhfast(float x) { return 2.0f / (1.0f + __expf(-2.0f * x)) - 1.0f; }

// --------------------------- pack kernels ----------------------------------

__global__ void pack_A_kernel(const float* __restrict__ x,
                              const float* __restrict__ h,
                              unsigned short* __restrict__ A) {
    const int total = B_ROWS * (D_K / 4);          // vec4 units, 512 per row
    for (int v = blockIdx.x * blockDim.x + threadIdx.x; v < total;
         v += gridDim.x * blockDim.x) {
        const int b = v >> 9;
        const int k0 = (v & 511) << 2;
        const float* src = (k0 < 1024) ? (x + (size_t)b * 1024 + k0)
                                       : (h + (size_t)b * 1024 + (k0 - 1024));
        float4 f = *(const float4*)src;
        unsigned p0 = (unsigned)f2bf(f.x) | ((unsigned)f2bf(f.y) << 16);
        unsigned p1 = (unsigned)f2bf(f.z) | ((unsigned)f2bf(f.w) << 16);
        uint2 o; o.x = p0; o.y = p1;
        *(uint2*)(A + (size_t)v * 4) = o;
    }
}

__global__ void pack_W_kernel(const float* __restrict__ Wx,
                              const float* __restrict__ Wh,
                              unsigned short* __restrict__ W) {
    const int total = 4096 * (D_K / 4);
    for (int v = blockIdx.x * blockDim.x + threadIdx.x; v < total;
         v += gridDim.x * blockDim.x) {
        const int n = v >> 9;                       // n = g*1024 + s
        const int k0 = (v & 511) << 2;
        const float* src = (k0 < 1024) ? (Wx + (size_t)n * 1024 + k0)
                                       : (Wh + (size_t)n * 1024 + (k0 - 1024));
        float4 f = *(const float4*)src;
        unsigned p0 = (unsigned)f2bf(f.x) | ((unsigned)f2bf(f.y) << 16);
        unsigned p1 = (unsigned)f2bf(f.z) | ((unsigned)f2bf(f.w) << 16);
        uint2 o; o.x = p0; o.y = p1;
        *(uint2*)(W + (size_t)v * 4) = o;
    }
}

__global__ void pack_bias_kernel(const float* __restrict__ bx,
                                 const float* __restrict__ bh,
                                 float* __restrict__ bias) {
    int i = blockIdx.x * blockDim.x + threadIdx.x;
    if (i < 4096) bias[i] = bx[i] + bh[i];
}

// --------------------------- fused GEMM ------------------------------------
// Tile: BM=128 rows (b), BN=64 cols (s) x 4 gates, BK=64.
// 512 threads = 8 waves: wr=wid>>1 (4 row groups of 32), wc=wid&1 (2 col
// groups of 32). Per wave: 32x32 per gate -> acc[4][2][2] f32x4 = 64 VGPR.

__global__ __launch_bounds__(512, 1) void lstm_gemm_kernel(
    const unsigned short* __restrict__ A,     // [16384][2048]
    const unsigned short* __restrict__ W,     // [4096][2048]
    const float* __restrict__ bias,           // [4096]
    const float* __restrict__ cell,           // [16384][1024]
    float* __restrict__ out) {                // new_c then h, each [16384][1024]
    // unified tile buffer: sA = elems [0, 8192), sW = elems [8192, 24576)
    // byte layout: 48 chunks of 1KB; chunk c holds 8 rows x 64 elems.
    __shared__ __align__(16) unsigned short smem[24576];

    // XCD-aware remap: 2048 blocks, 8 XCDs, 256 blocks/XCD (bijective).
    const int bid = blockIdx.x;
    const int wg = (bid & 7) * 256 + (bid >> 3);
    const int brow = (wg >> 4) << 7;          // row stripe * 128
    const int bcol = (wg & 15) << 6;          // col tile * 64

    const int tid = threadIdx.x;
    const int wid = tid >> 6;                 // 0..7
    const int lane = tid & 63;
    const int wr = wid >> 1, wc = wid & 1;
    const int lr = lane & 15, lg = lane >> 4;
    const int l8 = lane >> 3;                 // row within a 1KB staging chunk
    const int lcol = (lane & 7) << 3;         // k-offset (elems) within chunk

    f32x4 acc[4][2][2];
#pragma unroll
    for (int g = 0; g < 4; ++g)
#pragma unroll
        for (int m = 0; m < 2; ++m)
#pragma unroll
            for (int n = 0; n < 2; ++n) acc[g][m][n] = (f32x4){0.f, 0.f, 0.f, 0.f};

    // staging: 48 chunks (A: 0..15, W: 16..47), wave w owns chunks w*6..w*6+5
    const unsigned short* gp[6];
#pragma unroll
    for (int i = 0; i < 6; ++i) {
        const int c = wid * 6 + i;
        if (c < 16) {
            gp[i] = A + (size_t)(brow + c * 8 + l8) * D_K + lcol;
        } else {
            const int cw = c - 16;
            gp[i] = W + (size_t)((cw >> 3) * 1024 + bcol + (cw & 7) * 8 + l8) * D_K + lcol;
        }
    }

    // LDS dest: chunk base + row-in-chunk*128B + swizzled 16B slot
    // slot = (lane&7) ^ (row&7), row&7 == l8 here
    const int swz_off = l8 * 128 + (((lane & 7) ^ l8) << 4);
    char* dst = (char*)smem + wid * 6144 + swz_off;

    // prefetch first K-tile into registers
    uint4 rS[6];
#pragma unroll
    for (int i = 0; i < 6; ++i) rS[i] = *(const uint4*)(gp[i]);

    for (int kt = 0; kt < D_K; kt += 64) {
#pragma unroll
        for (int i = 0; i < 6; ++i) *(uint4*)(dst + i * 1024) = rS[i];
        __syncthreads();

        // issue next-tile loads early: latency hides under the MFMAs
        if (kt + 64 < D_K) {
#pragma unroll
            for (int i = 0; i < 6; ++i) rS[i] = *(const uint4*)(gp[i] + kt + 64);
        }

#pragma unroll
        for (int kk = 0; kk < 2; ++kk) {
            // swizzled k-column (elems); fragment row&7 == lr&7 everywhere
            const int swk = (kk * 32 + lg * 8) ^ ((lr & 7) << 3);
            bf16x8 a[2];
#pragma unroll
            for (int m = 0; m < 2; ++m)
                a[m] = *(const bf16x8*)&smem[(wr * 32 + m * 16 + lr) * 64 + swk];
#pragma unroll
            for (int g = 0; g < 4; ++g) {
                const int wbase = 8192 + (g * 64 + wc * 32 + lr) * 64 + swk;
                bf16x8 w0 = *(const bf16x8*)&smem[wbase];
                bf16x8 w1 = *(const bf16x8*)&smem[wbase + 16 * 64];
#pragma unroll
                for (int m = 0; m < 2; ++m) {
                    acc[g][m][0] = __builtin_amdgcn_mfma_f32_16x16x32_bf16(a[m], w0, acc[g][m][0], 0, 0, 0);
                    acc[g][m][1] = __builtin_amdgcn_mfma_f32_16x16x32_bf16(a[m], w1, acc[g][m][1], 0, 0, 0);
                }
            }
        }
        __syncthreads();
    }

    // fused epilogue: C/D layout col = lane&15, row = (lane>>4)*4 + reg
    float bv[4][2];
#pragma unroll
    for (int g = 0; g < 4; ++g)
#pragma unroll
        for (int n = 0; n < 2; ++n)
            bv[g][n] = bias[(g << 10) + bcol + wc * 32 + n * 16 + lr];

    float* outc = out;
    float* outh = out + (size_t)B_ROWS * 1024;
#pragma unroll
    for (int m = 0; m < 2; ++m) {
#pragma unroll
        for (int r = 0; r < 4; ++r) {
            const int b = brow + wr * 32 + m * 16 + lg * 4 + r;
            const size_t base = (size_t)b * 1024 + bcol + wc * 32;
#pragma unroll
            for (int n = 0; n < 2; ++n) {
                const int so = n * 16 + lr;
                float pf = acc[0][m][n][r] + bv[0][n];
                float pi = acc[1][m][n][r] + bv[1][n];
                float pc = acc[2][m][n][r] + bv[2][n];
                float po = acc[3][m][n][r] + bv[3][n];
                float cl = cell[base + so];
                float nc = cl * sigf(pf) + sigf(pi) * tanhfast(pc);
                outc[base + so] = nc;
                outh[base + so] = tanhfast(nc) * sigf(po);
            }
        }
    }
}

// ------------------- fp32 fallback (ws too small; slow but correct) --------

__global__ void lstm_naive_kernel(const float* __restrict__ x,
                                  const float* __restrict__ cell,
                                  const float* __restrict__ h,
                                  const float* __restrict__ Wx,
                                  const float* __restrict__ bx,
                                  const float* __restrict__ Wh,
                                  const float* __restrict__ bh,
                                  float* __restrict__ out) {
    int idx = blockIdx.x * blockDim.x + threadIdx.x;
    if (idx >= B_ROWS * 1024) return;
    int b = idx >> 10, s = idx & 1023;
    const float* xr = x + (size_t)b * 1024;
    const float* hr = h + (size_t)b * 1024;
    float pre[4];
#pragma unroll
    for (int g = 0; g < 4; ++g) {
        float acc = bx[(g << 10) + s] + bh[(g << 10) + s];
        const float* wx = Wx + ((size_t)(g << 10) + s) * 1024;
        const float* wh = Wh + ((size_t)(g << 10) + s) * 1024;
        for (int k = 0; k < 1024; ++k) acc += xr[k] * wx[k] + hr[k] * wh[k];
        pre[g] = acc;
    }
    float nc = cell[idx] * sigf(pre[0]) + sigf(pre[1]) * tanhfast(pre[2]);
    out[idx] = nc;
    out[(size_t)B_ROWS * 1024 + idx] = tanhfast(nc) * sigf(pre[3]);
}

// ---------------------------------------------------------------------------

extern "C" void kernel_launch(void* const* d_in, const int* in_sizes, int n_in,
                              void* d_out, int out_size, void* d_ws, size_t ws_size,
                              hipStream_t stream) {
    const float* x    = (const float*)d_in[0];
    const float* cell = (const float*)d_in[1];
    const float* hid  = (const float*)d_in[2];
    const float* Wx   = (const float*)d_in[3];
    const float* bx   = (const float*)d_in[4];
    const float* Wh   = (const float*)d_in[5];
    const float* bh   = (const float*)d_in[6];
    float* out = (float*)d_out;

    const size_t szA = (size_t)B_ROWS * D_K * 2;    // 64 MB
    const size_t szW = (size_t)4096 * D_K * 2;      // 16 MB
    const size_t szB = 4096 * 4;
    if (ws_size < szA + szW + szB) {
        lstm_naive_kernel<<<(B_ROWS * 1024) / 256, 256, 0, stream>>>(
            x, cell, hid, Wx, bx, Wh, bh, out);
        return;
    }

    unsigned short* Ab = (unsigned short*)d_ws;
    unsigned short* Wb = (unsigned short*)((char*)d_ws + szA);
    float* bias = (float*)((char*)d_ws + szA + szW);

    pack_A_kernel<<<8192, 256, 0, stream>>>(x, hid, Ab);
    pack_W_kernel<<<2048, 256, 0, stream>>>(Wx, Wh, Wb);
    pack_bias_kernel<<<16, 256, 0, stream>>>(bx, bh, bias);

    lstm_gemm_kernel<<<2048, 512, 0, stream>>>(Ab, Wb, bias, cell, out);
}

// Round 6
// 321.634 us; speedup vs baseline: 3.5909x; 3.5909x over previous
//
#include <hip/hip_runtime.h>
#include <hip/hip_bf16.h>
#include <stdint.h>

// ---------------------------------------------------------------------------
// LSTM cell, fused as one bf16 MFMA GEMM:
//   A  = [input | hidden]            : [16384][2048]  (bf16, packed in ws)
//   W  = [Wx[g] | Wh[g]] per gate g  : [4096][2048]   (bf16, packed in ws, [N][K])
//   pre[g][b][s] = sum_k A[b][k] * W[g*1024+s][k] + bias[g][s]
// Each block: 128x64 tile for ALL 4 gates, fused sigmoid/tanh/cell epilogue.
//
// Round 6 change (from falsified r5 theory + stronger spill evidence):
//   * WRITE_SIZE ~2.9-3.3GB across r3/r4/r5 matches threads*stagingBytes*
//     32iters*2048blk (3.2GB) for BOTH 256-thr/192B and 512-thr/96B variants
//     -> the reg-staged uint4s round-trip scratch every K-iter (arch VGPR=64,
//     acc lives in AGPRs; staging doesn't fit).
//   * Eliminate staging registers: global_load_lds (m97 path). LDS dest is
//     linear (HW: base + lane*16); swizzle is preserved by PRE-SWIZZLING the
//     global source column (col16 = (lane&7)^(lane>>3), m173/HK pattern) --
//     still 128B-coalesced per 8-lane row group. ds_read side unchanged
//     (verified: absmax 0.0156, bank conflicts 0).
//   * r1 post-timing-divergence mitigation: explicit s_waitcnt vmcnt(0)
//     before each __syncthreads so DMA completion never depends on
//     compiler-inserted waits.
// ---------------------------------------------------------------------------

typedef short bf16x8 __attribute__((ext_vector_type(8)));
typedef float f32x4 __attribute__((ext_vector_type(4)));

#define B_ROWS 16384
#define D_K 2048

__device__ __forceinline__ unsigned short f2bf(float f) {
    unsigned u = __builtin_bit_cast(unsigned, f);
    u += 0x7FFFu + ((u >> 16) & 1u);   // round-to-nearest-even
    return (unsigned short)(u >> 16);
}

__device__ __forceinline__ float sigf(float x) { return 1.0f / (1.0f + __expf(-x)); }
__device__ __forceinline__ float tanhfast(float x) { return 2.0f / (1.0f + __expf(-2.0f * x)) - 1.0f; }

// global -> LDS direct copy, 16B per lane; LDS dest wave-uniform base + lane*16.
#define GLD16(gp, lp)                                                          \
    __builtin_amdgcn_global_load_lds(                                          \
        (const __attribute__((address_space(1))) unsigned int*)(gp),           \
        (__attribute__((address_space(3))) unsigned int*)(lp), 16, 0, 0)

// --------------------------- pack kernels ----------------------------------

__global__ void pack_A_kernel(const float* __restrict__ x,
                              const float* __restrict__ h,
                              unsigned short* __restrict__ A) {
    const int total = B_ROWS * (D_K / 4);          // vec4 units, 512 per row
    for (int v = blockIdx.x * blockDim.x + threadIdx.x; v < total;
         v += gridDim.x * blockDim.x) {
        const int b = v >> 9;
        const int k0 = (v & 511) << 2;
        const float* src = (k0 < 1024) ? (x + (size_t)b * 1024 + k0)
                                       : (h + (size_t)b * 1024 + (k0 - 1024));
        float4 f = *(const float4*)src;
        unsigned p0 = (unsigned)f2bf(f.x) | ((unsigned)f2bf(f.y) << 16);
        unsigned p1 = (unsigned)f2bf(f.z) | ((unsigned)f2bf(f.w) << 16);
        uint2 o; o.x = p0; o.y = p1;
        *(uint2*)(A + (size_t)v * 4) = o;
    }
}

__global__ void pack_W_kernel(const float* __restrict__ Wx,
                              const float* __restrict__ Wh,
                              unsigned short* __restrict__ W) {
    const int total = 4096 * (D_K / 4);
    for (int v = blockIdx.x * blockDim.x + threadIdx.x; v < total;
         v += gridDim.x * blockDim.x) {
        const int n = v >> 9;                       // n = g*1024 + s
        const int k0 = (v & 511) << 2;
        const float* src = (k0 < 1024) ? (Wx + (size_t)n * 1024 + k0)
                                       : (Wh + (size_t)n * 1024 + (k0 - 1024));
        float4 f = *(const float4*)src;
        unsigned p0 = (unsigned)f2bf(f.x) | ((unsigned)f2bf(f.y) << 16);
        unsigned p1 = (unsigned)f2bf(f.z) | ((unsigned)f2bf(f.w) << 16);
        uint2 o; o.x = p0; o.y = p1;
        *(uint2*)(W + (size_t)v * 4) = o;
    }
}

__global__ void pack_bias_kernel(const float* __restrict__ bx,
                                 const float* __restrict__ bh,
                                 float* __restrict__ bias) {
    int i = blockIdx.x * blockDim.x + threadIdx.x;
    if (i < 4096) bias[i] = bx[i] + bh[i];
}

// --------------------------- fused GEMM ------------------------------------
// Tile: BM=128 rows (b), BN=64 cols (s) x 4 gates, BK=64.
// 512 threads = 8 waves: wr=wid>>1 (4 row groups of 32), wc=wid&1 (2 col
// groups of 32). Per wave: 32x32 per gate -> acc[4][2][2] f32x4 = 64 regs.

__global__ __launch_bounds__(512, 2) void lstm_gemm_kernel(
    const unsigned short* __restrict__ A,     // [16384][2048]
    const unsigned short* __restrict__ W,     // [4096][2048]
    const float* __restrict__ bias,           // [4096]
    const float* __restrict__ cell,           // [16384][1024]
    float* __restrict__ out) {                // new_c then h, each [16384][1024]
    // 48 chunks of 1KB; chunk c holds 8 rows x 64 elems (A: 0..15, W: 16..47)
    __shared__ __align__(16) unsigned short smem[24576];

    // XCD-aware remap: 2048 blocks, 8 XCDs, 256 blocks/XCD (bijective).
    const int bid = blockIdx.x;
    const int wg = (bid & 7) * 256 + (bid >> 3);
    const int brow = (wg >> 4) << 7;          // row stripe * 128
    const int bcol = (wg & 15) << 6;          // col tile * 64

    const int tid = threadIdx.x;
    const int wid = tid >> 6;                 // 0..7
    const int lane = tid & 63;
    const int wr = wid >> 1, wc = wid & 1;
    const int lr = lane & 15, lg = lane >> 4;
    const int l8 = lane >> 3;                 // row within a 1KB staging chunk
    // PRE-SWIZZLED global column: linear LDS slot (lane&7) must receive
    // global col ((lane&7)^l8)*8, so the ds_read-side XOR lands on data.
    const int lcol = (((lane & 7) ^ l8) << 3);

    f32x4 acc[4][2][2];
#pragma unroll
    for (int g = 0; g < 4; ++g)
#pragma unroll
        for (int m = 0; m < 2; ++m)
#pragma unroll
            for (int n = 0; n < 2; ++n) acc[g][m][n] = (f32x4){0.f, 0.f, 0.f, 0.f};

    // staging sources: wave w owns chunks w*6..w*6+5 (per-lane addresses)
    const unsigned short* gp[6];
#pragma unroll
    for (int i = 0; i < 6; ++i) {
        const int c = wid * 6 + i;
        if (c < 16) {
            gp[i] = A + (size_t)(brow + c * 8 + l8) * D_K + lcol;
        } else {
            const int cw = c - 16;
            gp[i] = W + (size_t)((cw >> 3) * 1024 + bcol + (cw & 7) * 8 + l8) * D_K + lcol;
        }
    }

    for (int kt = 0; kt < D_K; kt += 64) {
        // direct global->LDS DMA, no staging registers
#pragma unroll
        for (int i = 0; i < 6; ++i)
            GLD16(gp[i] + kt, (char*)smem + (wid * 6 + i) * 1024);
        asm volatile("s_waitcnt vmcnt(0)" ::: "memory");
        __syncthreads();

#pragma unroll
        for (int kk = 0; kk < 2; ++kk) {
            // swizzled k-column (elems); fragment row&7 == lr&7 everywhere
            const int swk = (kk * 32 + lg * 8) ^ ((lr & 7) << 3);
            bf16x8 a[2];
#pragma unroll
            for (int m = 0; m < 2; ++m)
                a[m] = *(const bf16x8*)&smem[(wr * 32 + m * 16 + lr) * 64 + swk];
#pragma unroll
            for (int g = 0; g < 4; ++g) {
                const int wbase = 8192 + (g * 64 + wc * 32 + lr) * 64 + swk;
                bf16x8 w0 = *(const bf16x8*)&smem[wbase];
                bf16x8 w1 = *(const bf16x8*)&smem[wbase + 16 * 64];
#pragma unroll
                for (int m = 0; m < 2; ++m) {
                    acc[g][m][0] = __builtin_amdgcn_mfma_f32_16x16x32_bf16(a[m], w0, acc[g][m][0], 0, 0, 0);
                    acc[g][m][1] = __builtin_amdgcn_mfma_f32_16x16x32_bf16(a[m], w1, acc[g][m][1], 0, 0, 0);
                }
            }
        }
        __syncthreads();
    }

    // fused epilogue: C/D layout col = lane&15, row = (lane>>4)*4 + reg
    float bv[4][2];
#pragma unroll
    for (int g = 0; g < 4; ++g)
#pragma unroll
        for (int n = 0; n < 2; ++n)
            bv[g][n] = bias[(g << 10) + bcol + wc * 32 + n * 16 + lr];

    float* outc = out;
    float* outh = out + (size_t)B_ROWS * 1024;
#pragma unroll
    for (int m = 0; m < 2; ++m) {
#pragma unroll
        for (int r = 0; r < 4; ++r) {
            const int b = brow + wr * 32 + m * 16 + lg * 4 + r;
            const size_t base = (size_t)b * 1024 + bcol + wc * 32;
#pragma unroll
            for (int n = 0; n < 2; ++n) {
                const int so = n * 16 + lr;
                float pf = acc[0][m][n][r] + bv[0][n];
                float pi = acc[1][m][n][r] + bv[1][n];
                float pc = acc[2][m][n][r] + bv[2][n];
                float po = acc[3][m][n][r] + bv[3][n];
                float cl = cell[base + so];
                float nc = cl * sigf(pf) + sigf(pi) * tanhfast(pc);
                outc[base + so] = nc;
                outh[base + so] = tanhfast(nc) * sigf(po);
            }
        }
    }
}

// ------------------- fp32 fallback (ws too small; slow but correct) --------

__global__ void lstm_naive_kernel(const float* __restrict__ x,
                                  const float* __restrict__ cell,
                                  const float* __restrict__ h,
                                  const float* __restrict__ Wx,
                                  const float* __restrict__ bx,
                                  const float* __restrict__ Wh,
                                  const float* __restrict__ bh,
                                  float* __restrict__ out) {
    int idx = blockIdx.x * blockDim.x + threadIdx.x;
    if (idx >= B_ROWS * 1024) return;
    int b = idx >> 10, s = idx & 1023;
    const float* xr = x + (size_t)b * 1024;
    const float* hr = h + (size_t)b * 1024;
    float pre[4];
#pragma unroll
    for (int g = 0; g < 4; ++g) {
        float acc = bx[(g << 10) + s] + bh[(g << 10) + s];
        const float* wx = Wx + ((size_t)(g << 10) + s) * 1024;
        const float* wh = Wh + ((size_t)(g << 10) + s) * 1024;
        for (int k = 0; k < 1024; ++k) acc += xr[k] * wx[k] + hr[k] * wh[k];
        pre[g] = acc;
    }
    float nc = cell[idx] * sigf(pre[0]) + sigf(pre[1]) * tanhfast(pre[2]);
    out[idx] = nc;
    out[(size_t)B_ROWS * 1024 + idx] = tanhfast(nc) * sigf(pre[3]);
}

// ---------------------------------------------------------------------------

extern "C" void kernel_launch(void* const* d_in, const int* in_sizes, int n_in,
                              void* d_out, int out_size, void* d_ws, size_t ws_size,
                              hipStream_t stream) {
    const float* x    = (const float*)d_in[0];
    const float* cell = (const float*)d_in[1];
    const float* hid  = (const float*)d_in[2];
    const float* Wx   = (const float*)d_in[3];
    const float* bx   = (const float*)d_in[4];
    const float* Wh   = (const float*)d_in[5];
    const float* bh   = (const float*)d_in[6];
    float* out = (float*)d_out;

    const size_t szA = (size_t)B_ROWS * D_K * 2;    // 64 MB
    const size_t szW = (size_t)4096 * D_K * 2;      // 16 MB
    const size_t szB = 4096 * 4;
    if (ws_size < szA + szW + szB) {
        lstm_naive_kernel<<<(B_ROWS * 1024) / 256, 256, 0, stream>>>(
            x, cell, hid, Wx, bx, Wh, bh, out);
        return;
    }

    unsigned short* Ab = (unsigned short*)d_ws;
    unsigned short* Wb = (unsigned short*)((char*)d_ws + szA);
    float* bias = (float*)((char*)d_ws + szA + szW);

    pack_A_kernel<<<8192, 256, 0, stream>>>(x, hid, Ab);
    pack_W_kernel<<<2048, 256, 0, stream>>>(Wx, Wh, Wb);
    pack_bias_kernel<<<16, 256, 0, stream>>>(bx, bh, bias);

    lstm_gemm_kernel<<<2048, 512, 0, stream>>>(Ab, Wb, bias, cell, out);
}

// Round 7
// 315.751 us; speedup vs baseline: 3.6578x; 1.0186x over previous
//
#include <hip/hip_runtime.h>
#include <hip/hip_bf16.h>
#include <stdint.h>

// ---------------------------------------------------------------------------
// LSTM cell, fused as one bf16 MFMA GEMM:
//   A  = [input | hidden]            : [16384][2048]  (bf16, packed in ws)
//   W  = [Wx[g] | Wh[g]] per gate g  : [4096][2048]   (bf16, packed in ws, [N][K])
//   pre[g][b][s] = sum_k A[b][k] * W[g*1024+s][k] + bias[g][s]
// Each block: 256 rows x 64 s-cols x 4 gates, fused sigmoid/tanh/cell epilogue.
//
// Round 7 changes (r6 confirmed spill theory: WRITE collapsed to 131MB =
// outputs; GEMM 290us @ MfmaUtil 44% -- single-buffered loop exposes full
// HBM latency every K-step, covered only by 2-block TLP ping-pong):
//   * T3/T4 "minimum 2-phase" double-buffer: issue next tile's 8
//     global_load_lds FIRST, then s_waitcnt vmcnt(8) (counted, never 0
//     mid-loop), raw s_barrier (no compiler vmcnt(0) drain), compute,
//     barrier. Loads stay in flight across barriers.
//   * m201-class reuse geometry: BM=256, wave tile 64r x 32s x 4 gates ->
//     acc[4][4][2] = 128 floats (safe: global_load_lds needs no staging
//     regs; ~190 VGPR < 256 budget @ (512,2)). MFMA:ds_read 64:24 = 2.67
//     (was 32:20 = 1.6).
//   * LDS 2 x 64KB = 128KB, 1 block/CU.
// ---------------------------------------------------------------------------

typedef short bf16x8 __attribute__((ext_vector_type(8)));
typedef float f32x4 __attribute__((ext_vector_type(4)));

#define B_ROWS 16384
#define D_K 2048

__device__ __forceinline__ unsigned short f2bf(float f) {
    unsigned u = __builtin_bit_cast(unsigned, f);
    u += 0x7FFFu + ((u >> 16) & 1u);   // round-to-nearest-even
    return (unsigned short)(u >> 16);
}

__device__ __forceinline__ float sigf(float x) { return 1.0f / (1.0f + __expf(-x)); }
__device__ __forceinline__ float tanhfast(float x) { return 2.0f / (1.0f + __expf(-2.0f * x)) - 1.0f; }

// global -> LDS direct copy, 16B per lane; LDS dest wave-uniform base + lane*16.
#define GLD16(gp, lp)                                                          \
    __builtin_amdgcn_global_load_lds(                                          \
        (const __attribute__((address_space(1))) unsigned int*)(gp),           \
        (__attribute__((address_space(3))) unsigned int*)(lp), 16, 0, 0)

// --------------------------- pack kernels ----------------------------------

__global__ void pack_A_kernel(const float* __restrict__ x,
                              const float* __restrict__ h,
                              unsigned short* __restrict__ A) {
    const int total = B_ROWS * (D_K / 4);          // vec4 units, 512 per row
    for (int v = blockIdx.x * blockDim.x + threadIdx.x; v < total;
         v += gridDim.x * blockDim.x) {
        const int b = v >> 9;
        const int k0 = (v & 511) << 2;
        const float* src = (k0 < 1024) ? (x + (size_t)b * 1024 + k0)
                                       : (h + (size_t)b * 1024 + (k0 - 1024));
        float4 f = *(const float4*)src;
        unsigned p0 = (unsigned)f2bf(f.x) | ((unsigned)f2bf(f.y) << 16);
        unsigned p1 = (unsigned)f2bf(f.z) | ((unsigned)f2bf(f.w) << 16);
        uint2 o; o.x = p0; o.y = p1;
        *(uint2*)(A + (size_t)v * 4) = o;
    }
}

__global__ void pack_W_kernel(const float* __restrict__ Wx,
                              const float* __restrict__ Wh,
                              unsigned short* __restrict__ W) {
    const int total = 4096 * (D_K / 4);
    for (int v = blockIdx.x * blockDim.x + threadIdx.x; v < total;
         v += gridDim.x * blockDim.x) {
        const int n = v >> 9;                       // n = g*1024 + s
        const int k0 = (v & 511) << 2;
        const float* src = (k0 < 1024) ? (Wx + (size_t)n * 1024 + k0)
                                       : (Wh + (size_t)n * 1024 + (k0 - 1024));
        float4 f = *(const float4*)src;
        unsigned p0 = (unsigned)f2bf(f.x) | ((unsigned)f2bf(f.y) << 16);
        unsigned p1 = (unsigned)f2bf(f.z) | ((unsigned)f2bf(f.w) << 16);
        uint2 o; o.x = p0; o.y = p1;
        *(uint2*)(W + (size_t)v * 4) = o;
    }
}

__global__ void pack_bias_kernel(const float* __restrict__ bx,
                                 const float* __restrict__ bh,
                                 float* __restrict__ bias) {
    int i = blockIdx.x * blockDim.x + threadIdx.x;
    if (i < 4096) bias[i] = bx[i] + bh[i];
}

// --------------------------- fused GEMM ------------------------------------
// Tile: BM=256 rows (b), 64 s-cols x 4 gates (256 W rows), BK=64.
// 512 threads = 8 waves: wr=wid>>1 (4 row groups of 64), wc=wid&1 (2 s-col
// groups of 32). Per wave: 64x32 per gate -> acc[4][4][2] f32x4 = 128 regs.

__global__ __launch_bounds__(512, 2) void lstm_gemm_kernel(
    const unsigned short* __restrict__ A,     // [16384][2048]
    const unsigned short* __restrict__ W,     // [4096][2048]
    const float* __restrict__ bias,           // [4096]
    const float* __restrict__ cell,           // [16384][1024]
    float* __restrict__ out) {                // new_c then h, each [16384][1024]
    // double-buffered: per buffer 64 chunks of 1KB (A: c 0..31, W: c 32..63);
    // chunk c holds 8 rows x 64 elems.
    __shared__ __align__(16) unsigned short smem[2][32768];

    // XCD-aware remap: 1024 blocks, 8 XCDs, 128 blocks/XCD (bijective).
    const int bid = blockIdx.x;
    const int wg = (bid & 7) * 128 + (bid >> 3);
    const int brow = (wg >> 4) << 8;          // 64 row tiles of 256
    const int bcol = (wg & 15) << 6;          // 16 col tiles of 64 (s within gate)

    const int tid = threadIdx.x;
    const int wid = tid >> 6;                 // 0..7
    const int lane = tid & 63;
    const int wr = wid >> 1, wc = wid & 1;
    const int lr = lane & 15, lg = lane >> 4;
    const int l8 = lane >> 3;                 // row within a 1KB staging chunk
    // PRE-SWIZZLED global column: linear LDS slot (lane&7) receives global
    // col ((lane&7)^l8)*8 so the ds_read-side XOR lands on the right data.
    const int lcol = (((lane & 7) ^ l8) << 3);

    f32x4 acc[4][4][2];
#pragma unroll
    for (int g = 0; g < 4; ++g)
#pragma unroll
        for (int m = 0; m < 4; ++m)
#pragma unroll
            for (int n = 0; n < 2; ++n) acc[g][m][n] = (f32x4){0.f, 0.f, 0.f, 0.f};

    // staging sources: wave w owns chunks w*8..w*8+7 (per-lane addresses)
    const unsigned short* gp[8];
#pragma unroll
    for (int i = 0; i < 8; ++i) {
        const int c = wid * 8 + i;
        if (c < 32) {
            gp[i] = A + (size_t)(brow + c * 8 + l8) * D_K + lcol;
        } else {
            const int cw = c - 32;
            gp[i] = W + (size_t)((cw >> 3) * 1024 + bcol + (cw & 7) * 8 + l8) * D_K + lcol;
        }
    }

    // per-buffer LDS destination base (bytes) for this wave's chunks
    char* const lds0 = (char*)smem + (size_t)wid * 8 * 1024;

#define STAGE(buf, kt)                                                         \
    do {                                                                       \
        char* _d = lds0 + (size_t)(buf) * 65536;                               \
        _Pragma("unroll")                                                      \
        for (int _i = 0; _i < 8; ++_i)                                         \
            GLD16(gp[_i] + (kt), _d + _i * 1024);                              \
    } while (0)

#define COMPUTE(buf)                                                           \
    do {                                                                       \
        const unsigned short* _sA = smem[buf];                                 \
        const unsigned short* _sW = smem[buf] + 16384;                         \
        _Pragma("unroll")                                                      \
        for (int kk = 0; kk < 2; ++kk) {                                       \
            const int swk = (kk * 32 + lg * 8) ^ ((lr & 7) << 3);              \
            bf16x8 a[4];                                                       \
            _Pragma("unroll")                                                  \
            for (int m = 0; m < 4; ++m)                                        \
                a[m] = *(const bf16x8*)&_sA[(wr * 64 + m * 16 + lr) * 64 + swk]; \
            _Pragma("unroll")                                                  \
            for (int g = 0; g < 4; ++g) {                                      \
                const int wbase = (g * 64 + wc * 32 + lr) * 64 + swk;          \
                bf16x8 w0 = *(const bf16x8*)&_sW[wbase];                       \
                bf16x8 w1 = *(const bf16x8*)&_sW[wbase + 16 * 64];             \
                _Pragma("unroll")                                              \
                for (int m = 0; m < 4; ++m) {                                  \
                    acc[g][m][0] = __builtin_amdgcn_mfma_f32_16x16x32_bf16(    \
                        a[m], w0, acc[g][m][0], 0, 0, 0);                      \
                    acc[g][m][1] = __builtin_amdgcn_mfma_f32_16x16x32_bf16(    \
                        a[m], w1, acc[g][m][1], 0, 0, 0);                      \
                }                                                              \
            }                                                                  \
        }                                                                      \
    } while (0)

    // prologue: stage first K-tile into buf 0
    STAGE(0, 0);

    int cur = 0;
    // main loop: 31 iterations with prefetch; loads never drain to 0
    for (int t = 0; t < 31; ++t) {
        STAGE(cur ^ 1, (t + 1) * 64);                 // 8 new loads in flight
        asm volatile("s_waitcnt vmcnt(8)" ::: "memory");  // drain buf[cur] only
        __builtin_amdgcn_s_barrier();
        asm volatile("" ::: "memory");
        COMPUTE(cur);
        asm volatile("" ::: "memory");
        __builtin_amdgcn_s_barrier();                 // all waves done reading
        asm volatile("" ::: "memory");
        cur ^= 1;
    }
    // epilogue tile: nothing left to prefetch
    asm volatile("s_waitcnt vmcnt(0)" ::: "memory");
    __builtin_amdgcn_s_barrier();
    asm volatile("" ::: "memory");
    COMPUTE(cur);

#undef STAGE
#undef COMPUTE

    // fused epilogue: C/D layout col = lane&15, row = (lane>>4)*4 + reg
    float bv[4][2];
#pragma unroll
    for (int g = 0; g < 4; ++g)
#pragma unroll
        for (int n = 0; n < 2; ++n)
            bv[g][n] = bias[(g << 10) + bcol + wc * 32 + n * 16 + lr];

    float* outc = out;
    float* outh = out + (size_t)B_ROWS * 1024;
#pragma unroll
    for (int m = 0; m < 4; ++m) {
#pragma unroll
        for (int r = 0; r < 4; ++r) {
            const int b = brow + wr * 64 + m * 16 + lg * 4 + r;
            const size_t base = (size_t)b * 1024 + bcol + wc * 32;
#pragma unroll
            for (int n = 0; n < 2; ++n) {
                const int so = n * 16 + lr;
                float pf = acc[0][m][n][r] + bv[0][n];
                float pi = acc[1][m][n][r] + bv[1][n];
                float pc = acc[2][m][n][r] + bv[2][n];
                float po = acc[3][m][n][r] + bv[3][n];
                float cl = cell[base + so];
                float nc = cl * sigf(pf) + sigf(pi) * tanhfast(pc);
                outc[base + so] = nc;
                outh[base + so] = tanhfast(nc) * sigf(po);
            }
        }
    }
}

// ------------------- fp32 fallback (ws too small; slow but correct) --------

__global__ void lstm_naive_kernel(const float* __restrict__ x,
                                  const float* __restrict__ cell,
                                  const float* __restrict__ h,
                                  const float* __restrict__ Wx,
                                  const float* __restrict__ bx,
                                  const float* __restrict__ Wh,
                                  const float* __restrict__ bh,
                                  float* __restrict__ out) {
    int idx = blockIdx.x * blockDim.x + threadIdx.x;
    if (idx >= B_ROWS * 1024) return;
    int b = idx >> 10, s = idx & 1023;
    const float* xr = x + (size_t)b * 1024;
    const float* hr = h + (size_t)b * 1024;
    float pre[4];
#pragma unroll
    for (int g = 0; g < 4; ++g) {
        float acc = bx[(g << 10) + s] + bh[(g << 10) + s];
        const float* wx = Wx + ((size_t)(g << 10) + s) * 1024;
        const float* wh = Wh + ((size_t)(g << 10) + s) * 1024;
        for (int k = 0; k < 1024; ++k) acc += xr[k] * wx[k] + hr[k] * wh[k];
        pre[g] = acc;
    }
    float nc = cell[idx] * sigf(pre[0]) + sigf(pre[1]) * tanhfast(pre[2]);
    out[idx] = nc;
    out[(size_t)B_ROWS * 1024 + idx] = tanhfast(nc) * sigf(pre[3]);
}

// ---------------------------------------------------------------------------

extern "C" void kernel_launch(void* const* d_in, const int* in_sizes, int n_in,
                              void* d_out, int out_size, void* d_ws, size_t ws_size,
                              hipStream_t stream) {
    const float* x    = (const float*)d_in[0];
    const float* cell = (const float*)d_in[1];
    const float* hid  = (const float*)d_in[2];
    const float* Wx   = (const float*)d_in[3];
    const float* bx   = (const float*)d_in[4];
    const float* Wh   = (const float*)d_in[5];
    const float* bh   = (const float*)d_in[6];
    float* out = (float*)d_out;

    const size_t szA = (size_t)B_ROWS * D_K * 2;    // 64 MB
    const size_t szW = (size_t)4096 * D_K * 2;      // 16 MB
    const size_t szB = 4096 * 4;
    if (ws_size < szA + szW + szB) {
        lstm_naive_kernel<<<(B_ROWS * 1024) / 256, 256, 0, stream>>>(
            x, cell, hid, Wx, bx, Wh, bh, out);
        return;
    }

    unsigned short* Ab = (unsigned short*)d_ws;
    unsigned short* Wb = (unsigned short*)((char*)d_ws + szA);
    float* bias = (float*)((char*)d_ws + szA + szW);

    pack_A_kernel<<<8192, 256, 0, stream>>>(x, hid, Ab);
    pack_W_kernel<<<2048, 256, 0, stream>>>(Wx, Wh, Wb);
    pack_bias_kernel<<<16, 256, 0, stream>>>(bx, bh, bias);

    lstm_gemm_kernel<<<1024, 512, 0, stream>>>(Ab, Wb, bias, cell, out);
}